// Round 8
// baseline (190.915 us; speedup 1.0000x reference)
//
#include <hip/hip_runtime.h>
#include <stdint.h>

#define N_BOXES 6000
#define NT 94            // ceil(6000/64) tiles of 64
#define NROWS (NT * 64)  // 6016 padded rows
#define CAP 64           // u16 suppression-list entries per row (sentinel 0xFFFF)
#define IOU_THR 0.5f
#define CONF_THR 0.6f

typedef unsigned long long u64;
typedef unsigned int u32;
typedef unsigned short u16;

// raw barrier: drain LDS only — global loads to registers may stay in flight
#define BAR() asm volatile("s_waitcnt lgkmcnt(0)\n\ts_barrier" ::: "memory")

__device__ __forceinline__ u64 rdlane64(u64 v, int l) {
    unsigned lo = (unsigned)__builtin_amdgcn_readlane((int)(unsigned)v, l);
    unsigned hi = (unsigned)__builtin_amdgcn_readlane((int)(unsigned)(v >> 32), l);
    return ((u64)hi << 32) | lo;
}

// ---- kernel 1: fused sort (keys + rank + scatter) + workspace init --------
// scores uniform [0,1) -> raw float bits monotone. key = (~bits<<32)|index:
// ascending u64 == descending score, ties by ascending index (JAX stable argsort).
// Compare source is wave-uniform -> scalar loads through K$ (no LDS, no VMEM
// pressure): each wave ranks its 64 boxes against a 1500-key segment.
__global__ void __launch_bounds__(256) k_sort(const float* __restrict__ scores,
                                              const float4* __restrict__ boxes,
                                              int* __restrict__ sidx,
                                              float4* __restrict__ sboxes,
                                              u32* __restrict__ lists_w,  // lists as u32
                                              int* __restrict__ cnt) {
    __shared__ int part[256];
    const int tid = threadIdx.x;
    const int gtid = blockIdx.x * 256 + tid;
    // init sparse-list sentinels + slot counters (spread over 24k threads)
    for (int j = gtid; j < NROWS * CAP / 2; j += NT * 256) lists_w[j] = 0xFFFFFFFFu;
    for (int j = gtid; j < NROWS; j += NT * 256) cnt[j] = 0;

    const int il = tid & 63;
    const int i = blockIdx.x * 64 + il;
    u64 mykey = 0;
    if (i < N_BOXES) {
        unsigned inv = ~__float_as_uint(scores[i]);
        mykey = ((u64)inv << 32) | (unsigned)i;
    }
    // wave-uniform segment start (readfirstlane makes uniformity explicit)
    const int j0u = __builtin_amdgcn_readfirstlane((tid >> 6) * 1500);
    int cntr = 0;
#pragma unroll 10
    for (int jj = 0; jj < 1500; ++jj) {
        const int u = j0u + jj;                       // uniform -> s_load
        unsigned sb = __float_as_uint(scores[u]);
        u64 kj = ((u64)(~sb) << 32) | (unsigned)u;
        cntr += (kj < mykey) ? 1 : 0;
    }
    part[tid] = cntr;
    __syncthreads();
    if (tid < 64 && i < N_BOXES) {
        int r = part[il] + part[64 + il] + part[128 + il] + part[192 + il];
        sidx[r] = i;                 // keys distinct -> permutation
        sboxes[r] = boxes[i];
    }
}

// ---- kernel 2: pairwise IoU -> SPARSE suppression lists + diag words ------
// In-tile (diagonal-block) edges go ONLY to diagw — k_scan's resolve handles
// them — so scatter in k_scan never touches removed[T] during tile T.
__global__ void k_mask(const float4* __restrict__ sboxes,
                       u16* __restrict__ lists, int* __restrict__ cnt,
                       u64* __restrict__ diagw) {
    int ct = blockIdx.x, rt = blockIdx.y;
    if (ct < rt) return;
    int lane = threadIdx.x;
    __shared__ float4 rb[64];
    int row0 = rt * 64;
    int rows = min(64, N_BOXES - row0);
    if (lane < rows) rb[lane] = sboxes[row0 + lane];
    __syncthreads();
    int j = ct * 64 + lane;
    bool jvalid = (j < N_BOXES);
    float4 cb = make_float4(0.f, 0.f, 1.f, 1.f);
    if (jvalid) cb = sboxes[j];
    float carea = (cb.z - cb.x) * (cb.w - cb.y);
    bool isdiag = (ct == rt);
    for (int i = 0; i < rows; ++i) {
        float4 rbx = rb[i];
        float rarea = (rbx.z - rbx.x) * (rbx.w - rbx.y);
        // identical f32 op order as the reference (_pairwise_iou)
        float iw = fmaxf(fminf(rbx.z, cb.z) - fmaxf(rbx.x, cb.x), 0.f);
        float ih = fmaxf(fminf(rbx.w, cb.w) - fmaxf(rbx.y, cb.y), 0.f);
        float inter = iw * ih;
        float iou = inter / ((rarea + carea) - inter);
        int row = row0 + i;
        bool pred = jvalid && (j > row) && (iou > IOU_THR);
        if (isdiag) {
            u64 bal = __ballot(pred);
            if (lane == (i & 63)) diagw[row] = bal;
        } else if (pred) {           // cross-tile edges only (~rare)
            int slot = atomicAdd(&cnt[row], 1);
            if (slot < CAP) lists[row * CAP + slot] = (u16)j;
        }
    }
}

// ---- kernel 3: greedy scan — redundant resolve, ONE barrier per tile ------
// Every wave loads the tile's diag words and resolves identically (uniform,
// ~1-3 bulk-keep iterations), so kw is in registers everywhere: no LDS
// publish round-trip. Scatter targets only tiles > T (in-tile edges live in
// diagw), so removed[T] is stable during tile T. One BAR per tile orders
// scatter(T) before resolve(T+1).
__global__ void __launch_bounds__(1024) k_scan(const u16* __restrict__ lists,
                                               const u64* __restrict__ diagw,
                                               const int* __restrict__ sidx,
                                               const float* __restrict__ scores,
                                               float* __restrict__ out) {
    __shared__ u64 removed[NT];
    __shared__ u64 kwbuf[NT];
    const int tid   = threadIdx.x;
    const int lane  = tid & 63;
    const int row_l = tid >> 4;              // local row 0..63
    const int sg    = (tid & 15) * 4;        // entry-group start (4 u16 = 8 B)
    if (tid < NT) removed[tid] = 0;

    u64 LA, LB, dA, dB;
    LA = *(const u64*)&lists[(0 * 64 + row_l) * CAP + sg];   // tile 0 entries
    dA = diagw[lane];                                        // tile 0 diag (every wave)
    dB = 0;
    __syncthreads();   // full barrier once (covers removed[] init)

#define STEP(T, LUSE, LFILL, DUSE, DFILL)                                      \
    {                                                                          \
        const int tn = ((T) + 1 < NT) ? ((T) + 1) : 0;                         \
        LFILL = *(const u64*)&lists[(tn * 64 + row_l) * CAP + sg];             \
        DFILL = diagw[tn * 64 + lane];                       /* prefetch */    \
        const u64 nz = __ballot(DUSE != 0ull);   /* in-tile suppressors */     \
        const int row0 = (T) * 64;                                             \
        const int rows = (N_BOXES - row0 >= 64) ? 64 : (N_BOXES - row0);       \
        const u64 valid = (rows == 64) ? ~0ull : ((1ull << rows) - 1ull);      \
        u64 c = valid & ~removed[(T)];                                         \
        u64 kw = 0;                                                            \
        while (c) {                                                            \
            u64 blockers = c & nz;                                             \
            if (!blockers) { kw |= c; break; }     /* bulk-keep rest */        \
            int g = (int)__builtin_ctzll(blockers);                            \
            u64 below = c & ((1ull << g) - 1ull);  /* zero-diag: kept */       \
            kw |= below | (1ull << g);                                         \
            u64 df = rdlane64(DUSE, g);            /* bits > g only */         \
            c &= ~(df | below | (1ull << g));                                  \
        }                                                                      \
        if (tid == 0) kwbuf[(T)] = kw;                                         \
        if (((kw >> row_l) & 1ull) && LUSE != ~0ull) {                         \
            u16 e0 = (u16)(LUSE), e1 = (u16)(LUSE >> 16),                      \
                e2 = (u16)(LUSE >> 32), e3 = (u16)(LUSE >> 48);                \
            if (e0 != 0xFFFFu) atomicOr(&removed[e0 >> 6], 1ull << (e0 & 63)); \
            if (e1 != 0xFFFFu) atomicOr(&removed[e1 >> 6], 1ull << (e1 & 63)); \
            if (e2 != 0xFFFFu) atomicOr(&removed[e2 >> 6], 1ull << (e2 & 63)); \
            if (e3 != 0xFFFFu) atomicOr(&removed[e3 >> 6], 1ull << (e3 & 63)); \
        }                                                                      \
        BAR();                                                                 \
    }

    for (int t = 0; t < NT; t += 2) {        // NT = 94 (even)
        STEP(t,     LA, LB, dA, dB)
        STEP(t + 1, LB, LA, dB, dA)
    }
#undef STEP

    // ---- epilogue: masked scores through the sort permutation ----
    for (int p = tid; p < N_BOXES; p += 1024) {
        int orig = sidx[p];
        float s = scores[orig];
        bool k = (kwbuf[p >> 6] >> (p & 63)) & 1ull;
        out[orig] = (k && (s >= CONF_THR)) ? s : 0.0f;  // writes ALL outputs
    }
}

extern "C" void kernel_launch(void* const* d_in, const int* in_sizes, int n_in,
                              void* d_out, int out_size, void* d_ws, size_t ws_size,
                              hipStream_t stream) {
    const float* boxes  = (const float*)d_in[0];    // [6000,4]
    const float* scores = (const float*)d_in[1];    // [6000]
    float* out = (float*)d_out;                     // [6000]

    // workspace layout
    char* ws = (char*)d_ws;
    u16*    lists  = (u16*)(ws);                    // 6016*64*2 = 770,048 B
    int*    cnt    = (int*)(ws + 770048);           // 6016*4    =  24,064 B
    u64*    diagw  = (u64*)(ws + 794112);           // 94*64*8   =  48,128 B
    int*    sidx   = (int*)(ws + 842240);           // 24,000 B
    float4* sboxes = (float4*)(ws + 866240);        // 96,000 B (16B aligned)

    k_sort<<<dim3(NT), dim3(256), 0, stream>>>(scores, (const float4*)boxes, sidx,
                                               sboxes, (u32*)lists, cnt);
    k_mask<<<dim3(NT, NT), dim3(64), 0, stream>>>((const float4*)sboxes, lists, cnt, diagw);
    k_scan<<<dim3(1), dim3(1024), 0, stream>>>(lists, diagw, sidx, scores, out);
}

// Round 9
// 142.435 us; speedup vs baseline: 1.3404x; 1.3404x over previous
//
#include <hip/hip_runtime.h>
#include <stdint.h>

#define N_BOXES 6000
#define NT 94            // ceil(6000/64) tiles of 64
#define NROWS (NT * 64)  // 6016 padded rows
#define CAP 64           // u16 suppression-list entries per row (sentinel 0xFFFF)
#define IOU_THR 0.5f
#define CONF_THR 0.6f

typedef unsigned long long u64;
typedef unsigned int u32;
typedef unsigned short u16;

// raw barrier: drain LDS only — global loads to registers may stay in flight
#define BAR() asm volatile("s_waitcnt lgkmcnt(0)\n\ts_barrier" ::: "memory")

__device__ __forceinline__ u64 rdlane64(u64 v, int l) {
    unsigned lo = (unsigned)__builtin_amdgcn_readlane((int)(unsigned)v, l);
    unsigned hi = (unsigned)__builtin_amdgcn_readlane((int)(unsigned)(v >> 32), l);
    return ((u64)hi << 32) | lo;
}

// ---- kernel 1: fused sort (keys + rank + scatter) + workspace init --------
// scores uniform [0,1) -> raw float bits monotone. key = (~bits<<32)|index:
// ascending u64 == descending score, ties by ascending index (JAX stable argsort).
// LDS-staged keys, broadcast ds_read compares (R8's scalar-pipe attempt
// regressed: compiler emits serialized global loads, not s_load — reverted).
// 1024 threads: 16 segments x 375 keys -> 4x shorter per-thread chain than R6.
__global__ void __launch_bounds__(1024) k_sort(const float* __restrict__ scores,
                                               const float4* __restrict__ boxes,
                                               int* __restrict__ sidx,
                                               float4* __restrict__ sboxes,
                                               u32* __restrict__ lists_w,  // lists as u32
                                               int* __restrict__ cnt) {
    __shared__ u64 kt[N_BOXES];      // 48,000 B
    __shared__ int part[1024];
    const int tid = threadIdx.x;
    const int gtid = blockIdx.x * 1024 + tid;
    // init sparse-list sentinels + slot counters (spread over 96k threads)
    for (int j = gtid; j < NROWS * CAP / 2; j += NT * 1024) lists_w[j] = 0xFFFFFFFFu;
    for (int j = gtid; j < NROWS; j += NT * 1024) cnt[j] = 0;

    for (int j = tid; j < N_BOXES; j += 1024) {
        unsigned inv = ~__float_as_uint(scores[j]);
        kt[j] = ((u64)inv << 32) | (unsigned)j;
    }
    __syncthreads();
    const int il = tid & 63;
    const int i = blockIdx.x * 64 + il;
    const int j0 = (tid >> 6) * 375;         // 16 segments of 375 (wave-uniform)
    u64 mykey = (i < N_BOXES) ? kt[i] : 0ull;
    int cntr = 0;
#pragma unroll 5
    for (int jj = 0; jj < 375; ++jj)
        cntr += (kt[j0 + jj] < mykey) ? 1 : 0;
    part[tid] = cntr;
    __syncthreads();
    if (tid < 64 && i < N_BOXES) {
        int r = 0;
#pragma unroll
        for (int s = 0; s < 16; ++s) r += part[il + 64 * s];
        sidx[r] = i;                 // keys distinct -> permutation
        sboxes[r] = boxes[i];
    }
}

// ---- kernel 2: pairwise IoU -> SPARSE suppression lists + diag words ------
// In-tile (diagonal-block) edges go ONLY to diagw — k_scan's resolve handles
// them — so scatter in k_scan never touches removed[T] during tile T.
__global__ void k_mask(const float4* __restrict__ sboxes,
                       u16* __restrict__ lists, int* __restrict__ cnt,
                       u64* __restrict__ diagw) {
    int ct = blockIdx.x, rt = blockIdx.y;
    if (ct < rt) return;
    int lane = threadIdx.x;
    __shared__ float4 rb[64];
    int row0 = rt * 64;
    int rows = min(64, N_BOXES - row0);
    if (lane < rows) rb[lane] = sboxes[row0 + lane];
    __syncthreads();
    int j = ct * 64 + lane;
    bool jvalid = (j < N_BOXES);
    float4 cb = make_float4(0.f, 0.f, 1.f, 1.f);
    if (jvalid) cb = sboxes[j];
    float carea = (cb.z - cb.x) * (cb.w - cb.y);
    bool isdiag = (ct == rt);
    for (int i = 0; i < rows; ++i) {
        float4 rbx = rb[i];
        float rarea = (rbx.z - rbx.x) * (rbx.w - rbx.y);
        // identical f32 op order as the reference (_pairwise_iou)
        float iw = fmaxf(fminf(rbx.z, cb.z) - fmaxf(rbx.x, cb.x), 0.f);
        float ih = fmaxf(fminf(rbx.w, cb.w) - fmaxf(rbx.y, cb.y), 0.f);
        float inter = iw * ih;
        float iou = inter / ((rarea + carea) - inter);
        int row = row0 + i;
        bool pred = jvalid && (j > row) && (iou > IOU_THR);
        if (isdiag) {
            u64 bal = __ballot(pred);
            if (lane == (i & 63)) diagw[row] = bal;
        } else if (pred) {           // cross-tile edges only (~rare)
            int slot = atomicAdd(&cnt[row], 1);
            if (slot < CAP) lists[row * CAP + slot] = (u16)j;
        }
    }
}

// ---- kernel 3: greedy scan — redundant resolve, ONE barrier per tile ------
// Every wave loads the tile's diag words and resolves identically (uniform,
// ~1-3 bulk-keep iterations), so kw is in registers everywhere: no LDS
// publish round-trip. Scatter targets only tiles > T (in-tile edges live in
// diagw), so removed[T] is stable during tile T. One BAR per tile orders
// scatter(T) before resolve(T+1).
__global__ void __launch_bounds__(1024) k_scan(const u16* __restrict__ lists,
                                               const u64* __restrict__ diagw,
                                               const int* __restrict__ sidx,
                                               const float* __restrict__ scores,
                                               float* __restrict__ out) {
    __shared__ u64 removed[NT];
    __shared__ u64 kwbuf[NT];
    const int tid   = threadIdx.x;
    const int lane  = tid & 63;
    const int row_l = tid >> 4;              // local row 0..63
    const int sg    = (tid & 15) * 4;        // entry-group start (4 u16 = 8 B)
    if (tid < NT) removed[tid] = 0;

    u64 LA, LB, dA, dB;
    LA = *(const u64*)&lists[(0 * 64 + row_l) * CAP + sg];   // tile 0 entries
    dA = diagw[lane];                                        // tile 0 diag (every wave)
    dB = 0;
    __syncthreads();   // full barrier once (covers removed[] init)

#define STEP(T, LUSE, LFILL, DUSE, DFILL)                                      \
    {                                                                          \
        const int tn = ((T) + 1 < NT) ? ((T) + 1) : 0;                         \
        LFILL = *(const u64*)&lists[(tn * 64 + row_l) * CAP + sg];             \
        DFILL = diagw[tn * 64 + lane];                       /* prefetch */    \
        const u64 nz = __ballot(DUSE != 0ull);   /* in-tile suppressors */     \
        const int row0 = (T) * 64;                                             \
        const int rows = (N_BOXES - row0 >= 64) ? 64 : (N_BOXES - row0);       \
        const u64 valid = (rows == 64) ? ~0ull : ((1ull << rows) - 1ull);      \
        u64 c = valid & ~removed[(T)];                                         \
        u64 kw = 0;                                                            \
        while (c) {                                                            \
            u64 blockers = c & nz;                                             \
            if (!blockers) { kw |= c; break; }     /* bulk-keep rest */        \
            int g = (int)__builtin_ctzll(blockers);                            \
            u64 below = c & ((1ull << g) - 1ull);  /* zero-diag: kept */       \
            kw |= below | (1ull << g);                                         \
            u64 df = rdlane64(DUSE, g);            /* bits > g only */         \
            c &= ~(df | below | (1ull << g));                                  \
        }                                                                      \
        if (tid == 0) kwbuf[(T)] = kw;                                         \
        if (((kw >> row_l) & 1ull) && LUSE != ~0ull) {                         \
            u16 e0 = (u16)(LUSE), e1 = (u16)(LUSE >> 16),                      \
                e2 = (u16)(LUSE >> 32), e3 = (u16)(LUSE >> 48);                \
            if (e0 != 0xFFFFu) atomicOr(&removed[e0 >> 6], 1ull << (e0 & 63)); \
            if (e1 != 0xFFFFu) atomicOr(&removed[e1 >> 6], 1ull << (e1 & 63)); \
            if (e2 != 0xFFFFu) atomicOr(&removed[e2 >> 6], 1ull << (e2 & 63)); \
            if (e3 != 0xFFFFu) atomicOr(&removed[e3 >> 6], 1ull << (e3 & 63)); \
        }                                                                      \
        BAR();                                                                 \
    }

    for (int t = 0; t < NT; t += 2) {        // NT = 94 (even)
        STEP(t,     LA, LB, dA, dB)
        STEP(t + 1, LB, LA, dB, dA)
    }
#undef STEP

    // ---- epilogue: masked scores through the sort permutation ----
    for (int p = tid; p < N_BOXES; p += 1024) {
        int orig = sidx[p];
        float s = scores[orig];
        bool k = (kwbuf[p >> 6] >> (p & 63)) & 1ull;
        out[orig] = (k && (s >= CONF_THR)) ? s : 0.0f;  // writes ALL outputs
    }
}

extern "C" void kernel_launch(void* const* d_in, const int* in_sizes, int n_in,
                              void* d_out, int out_size, void* d_ws, size_t ws_size,
                              hipStream_t stream) {
    const float* boxes  = (const float*)d_in[0];    // [6000,4]
    const float* scores = (const float*)d_in[1];    // [6000]
    float* out = (float*)d_out;                     // [6000]

    // workspace layout
    char* ws = (char*)d_ws;
    u16*    lists  = (u16*)(ws);                    // 6016*64*2 = 770,048 B
    int*    cnt    = (int*)(ws + 770048);           // 6016*4    =  24,064 B
    u64*    diagw  = (u64*)(ws + 794112);           // 94*64*8   =  48,128 B
    int*    sidx   = (int*)(ws + 842240);           // 24,000 B
    float4* sboxes = (float4*)(ws + 866240);        // 96,000 B (16B aligned)

    k_sort<<<dim3(NT), dim3(1024), 0, stream>>>(scores, (const float4*)boxes, sidx,
                                                sboxes, (u32*)lists, cnt);
    k_mask<<<dim3(NT, NT), dim3(64), 0, stream>>>((const float4*)sboxes, lists, cnt, diagw);
    k_scan<<<dim3(1), dim3(1024), 0, stream>>>(lists, diagw, sidx, scores, out);
}

// Round 10
// 132.718 us; speedup vs baseline: 1.4385x; 1.0732x over previous
//
#include <hip/hip_runtime.h>
#include <stdint.h>

#define N_BOXES 6000
#define NT 94            // real tiles of 64
#define NTP 96           // padded tile count (unroll-3 pipeline)
#define NROWS (NTP * 64) // 6144 padded rows
#define CAP 16           // u16 suppression-list entries per row (sentinel 0xFFFF)
#define IOU_THR 0.5f
#define CONF_THR 0.6f

typedef unsigned long long u64;
typedef unsigned int u32;
typedef unsigned short u16;

// raw barrier: drain LDS only — global loads to registers may stay in flight
#define BAR() asm volatile("s_waitcnt lgkmcnt(0)\n\ts_barrier" ::: "memory")

__device__ __forceinline__ u64 rdlane64(u64 v, int l) {
    unsigned lo = (unsigned)__builtin_amdgcn_readlane((int)(unsigned)v, l);
    unsigned hi = (unsigned)__builtin_amdgcn_readlane((int)(unsigned)(v >> 32), l);
    return ((u64)hi << 32) | lo;
}

// ---- kernel 1: fused sort (keys + rank + scatter) + workspace init --------
// scores uniform [0,1) -> raw float bits monotone. key = (~bits<<32)|index:
// ascending u64 == descending score, ties by ascending index (JAX stable argsort).
// LDS-staged keys, broadcast ds_read compares (scalar-pipe attempt in R8
// regressed: compiler emits serialized global loads, not s_load).
__global__ void __launch_bounds__(1024) k_sort(const float* __restrict__ scores,
                                               const float4* __restrict__ boxes,
                                               int* __restrict__ sidx,
                                               float4* __restrict__ sboxes,
                                               u32* __restrict__ lists_w,  // lists as u32
                                               int* __restrict__ cnt) {
    __shared__ u64 kt[N_BOXES];      // 48,000 B
    __shared__ int part[1024];
    const int tid = threadIdx.x;
    const int gtid = blockIdx.x * 1024 + tid;
    // init sparse-list sentinels + slot counters (spread over 96k threads)
    for (int j = gtid; j < NROWS * CAP / 2; j += NT * 1024) lists_w[j] = 0xFFFFFFFFu;
    for (int j = gtid; j < NROWS; j += NT * 1024) cnt[j] = 0;

    for (int j = tid; j < N_BOXES; j += 1024) {
        unsigned inv = ~__float_as_uint(scores[j]);
        kt[j] = ((u64)inv << 32) | (unsigned)j;
    }
    __syncthreads();
    const int il = tid & 63;
    const int i = blockIdx.x * 64 + il;
    const int j0 = (tid >> 6) * 375;         // 16 segments of 375 (wave-uniform)
    u64 mykey = (i < N_BOXES) ? kt[i] : 0ull;
    int cntr = 0;
#pragma unroll 5
    for (int jj = 0; jj < 375; ++jj)
        cntr += (kt[j0 + jj] < mykey) ? 1 : 0;
    part[tid] = cntr;
    __syncthreads();
    if (tid < 64 && i < N_BOXES) {
        int r = 0;
#pragma unroll
        for (int s = 0; s < 16; ++s) r += part[il + 64 * s];
        sidx[r] = i;                 // keys distinct -> permutation
        sboxes[r] = boxes[i];
    }
}

// ---- kernel 2: pairwise IoU -> SPARSE suppression lists + diag words ------
// In-tile (diagonal-block) edges go ONLY to diagw — k_scan's resolve handles
// them — so scatter in k_scan never touches removed[T] during tile T.
__global__ void k_mask(const float4* __restrict__ sboxes,
                       u16* __restrict__ lists, int* __restrict__ cnt,
                       u64* __restrict__ diagw) {
    int ct = blockIdx.x, rt = blockIdx.y;
    if (ct < rt) return;
    int lane = threadIdx.x;
    __shared__ float4 rb[64];
    int row0 = rt * 64;
    int rows = min(64, N_BOXES - row0);
    if (lane < rows) rb[lane] = sboxes[row0 + lane];
    __syncthreads();
    int j = ct * 64 + lane;
    bool jvalid = (j < N_BOXES);
    float4 cb = make_float4(0.f, 0.f, 1.f, 1.f);
    if (jvalid) cb = sboxes[j];
    float carea = (cb.z - cb.x) * (cb.w - cb.y);
    bool isdiag = (ct == rt);
    for (int i = 0; i < rows; ++i) {
        float4 rbx = rb[i];
        float rarea = (rbx.z - rbx.x) * (rbx.w - rbx.y);
        // identical f32 op order as the reference (_pairwise_iou)
        float iw = fmaxf(fminf(rbx.z, cb.z) - fmaxf(rbx.x, cb.x), 0.f);
        float ih = fmaxf(fminf(rbx.w, cb.w) - fmaxf(rbx.y, cb.y), 0.f);
        float inter = iw * ih;
        float iou = inter / ((rarea + carea) - inter);
        int row = row0 + i;
        bool pred = jvalid && (j > row) && (iou > IOU_THR);
        if (isdiag) {
            u64 bal = __ballot(pred);
            if (lane == (i & 63)) diagw[row] = bal;
        } else if (pred) {           // cross-tile edges only (~rare)
            int slot = atomicAdd(&cnt[row], 1);
            if (slot < CAP) lists[row * CAP + slot] = (u16)j;
        }
    }
}

// ---- kernel 3: greedy scan — 4 waves, distance-3 prefetch, CAP=16 ---------
// 256 threads: row_l = tid>>2 (4 threads/row), each holds 4 u16 entries (8B).
// 3 rotating buffers, loads issued 3 tiles (~900 cyc) before consumption —
// covers remote-XCD/HBM latency. All 4 waves redundantly resolve (identical
// diag registers), so kw is register-resident everywhere; 1 barrier/tile.
// Pad tiles 94,95: valid=0 -> kw=0 -> no scatter (diag garbage harmless).
__global__ void __launch_bounds__(256) k_scan(const u16* __restrict__ lists,
                                              const u64* __restrict__ diagw,
                                              const int* __restrict__ sidx,
                                              const float* __restrict__ scores,
                                              float* __restrict__ out) {
    __shared__ u64 removed[NTP];
    __shared__ u64 kwbuf[NTP];
    const int tid   = threadIdx.x;
    const int lane  = tid & 63;
    const int row_l = tid >> 2;              // local row 0..63
    const int sg    = (tid & 3) * 4;         // entry-group start (4 u16 = 8 B)
    if (tid < NTP) removed[tid] = 0;

    u64 L0, L1, L2, D0, D1, D2;
    L0 = *(const u64*)&lists[(0 * 64 + row_l) * CAP + sg];
    L1 = *(const u64*)&lists[(1 * 64 + row_l) * CAP + sg];
    L2 = *(const u64*)&lists[(2 * 64 + row_l) * CAP + sg];
    D0 = diagw[0 * 64 + lane];
    D1 = diagw[1 * 64 + lane];
    D2 = diagw[2 * 64 + lane];
    __syncthreads();   // full barrier once (covers removed[] init)

#define STEP(T, LUSE, DUSE)                                                    \
    {                                                                          \
        const u64 nz = __ballot(DUSE != 0ull);   /* in-tile suppressors */     \
        const int row0 = (T) * 64;                                             \
        const int rem = N_BOXES - row0;                                        \
        const u64 valid = (rem >= 64) ? ~0ull                                  \
                        : ((rem <= 0) ? 0ull : ((1ull << rem) - 1ull));        \
        u64 c = valid & ~removed[(T)];                                         \
        u64 kw = 0;                                                            \
        while (c) {                                                            \
            u64 blockers = c & nz;                                             \
            if (!blockers) { kw |= c; break; }     /* bulk-keep rest */        \
            int g = (int)__builtin_ctzll(blockers);                            \
            u64 below = c & ((1ull << g) - 1ull);  /* zero-diag: kept */       \
            kw |= below | (1ull << g);                                         \
            u64 df = rdlane64(DUSE, g);            /* bits > g only */         \
            c &= ~(df | below | (1ull << g));                                  \
        }                                                                      \
        if (tid == 0) kwbuf[(T)] = kw;                                         \
        if (((kw >> row_l) & 1ull) && LUSE != ~0ull) {                         \
            u16 e0 = (u16)(LUSE), e1 = (u16)(LUSE >> 16),                      \
                e2 = (u16)(LUSE >> 32), e3 = (u16)(LUSE >> 48);                \
            if (e0 != 0xFFFFu) atomicOr(&removed[e0 >> 6], 1ull << (e0 & 63)); \
            if (e1 != 0xFFFFu) atomicOr(&removed[e1 >> 6], 1ull << (e1 & 63)); \
            if (e2 != 0xFFFFu) atomicOr(&removed[e2 >> 6], 1ull << (e2 & 63)); \
            if (e3 != 0xFFFFu) atomicOr(&removed[e3 >> 6], 1ull << (e3 & 63)); \
        }                                                                      \
        const int tn = ((T) + 3 < NTP) ? ((T) + 3) : ((T) + 3 - NTP);          \
        LUSE = *(const u64*)&lists[(tn * 64 + row_l) * CAP + sg];              \
        DUSE = diagw[tn * 64 + lane];                                          \
        BAR();                                                                 \
    }

    for (int t = 0; t < NTP; t += 3) {       // NTP = 96 = 32 x 3
        STEP(t,     L0, D0)
        STEP(t + 1, L1, D1)
        STEP(t + 2, L2, D2)
    }
#undef STEP

    // ---- epilogue: masked scores through the sort permutation ----
    for (int p = tid; p < N_BOXES; p += 256) {
        int orig = sidx[p];
        float s = scores[orig];
        bool k = (kwbuf[p >> 6] >> (p & 63)) & 1ull;
        out[orig] = (k && (s >= CONF_THR)) ? s : 0.0f;  // writes ALL outputs
    }
}

extern "C" void kernel_launch(void* const* d_in, const int* in_sizes, int n_in,
                              void* d_out, int out_size, void* d_ws, size_t ws_size,
                              hipStream_t stream) {
    const float* boxes  = (const float*)d_in[0];    // [6000,4]
    const float* scores = (const float*)d_in[1];    // [6000]
    float* out = (float*)d_out;                     // [6000]

    // workspace layout
    char* ws = (char*)d_ws;
    u16*    lists  = (u16*)(ws);                    // 6144*16*2 = 196,608 B
    int*    cnt    = (int*)(ws + 196608);           // 6144*4    =  24,576 B
    u64*    diagw  = (u64*)(ws + 221184);           // 96*64*8   =  49,152 B
    int*    sidx   = (int*)(ws + 270336);           // 24,000 B
    float4* sboxes = (float4*)(ws + 294336);        // 96,000 B (16B aligned)

    k_sort<<<dim3(NT), dim3(1024), 0, stream>>>(scores, (const float4*)boxes, sidx,
                                                sboxes, (u32*)lists, cnt);
    k_mask<<<dim3(NT, NT), dim3(64), 0, stream>>>((const float4*)sboxes, lists, cnt, diagw);
    k_scan<<<dim3(1), dim3(256), 0, stream>>>(lists, diagw, sidx, scores, out);
}